// Round 9
// baseline (216.185 us; speedup 1.0000x reference)
//
#include <hip/hip_runtime.h>

#define N_NODES 100000
#define IN_CH 128
#define HID_CH 256
#define OUT_CH 128
#define N_EDGES 1600000

#define NBK 782                                   // ceil(N_NODES/128) buckets of 128 nodes
#define BIN_BLOCKS 256
#define EPB (N_EDGES / BIN_BLOCKS)                // 6250 edges per bin block
#define GG_CAP 4096                               // per-bucket edge cap (mean 2048, sigma 45)

typedef __attribute__((ext_vector_type(8))) short short8;
typedef __attribute__((ext_vector_type(4))) float f32x4;

// bf16 <-> f32 helpers (bit ops; finite data only)
__device__ __forceinline__ float b2f(ushort u) {
    unsigned int x = ((unsigned int)u) << 16;
    return __uint_as_float(x);
}
__device__ __forceinline__ ushort f2b(float f) {
    unsigned int u = __float_as_uint(f);
    u += 0x7FFFu + ((u >> 16) & 1u);   // round-to-nearest-even
    return (ushort)(u >> 16);
}

// ---------------------------------------------------------------------------
// Prep (+ fused ghist): x fp32 -> xb bf16 ; W1 -> W1T ; W2 -> W2T ;
// last 256 blocks: per-(block,bucket) dst histogram (transposed store).
// ---------------------------------------------------------------------------
#define PREP_X_BLOCKS 6250
#define PREP_W1_BLOCKS 128
#define PREP_W2_BLOCKS 128
#define PREP_TOTAL (PREP_X_BLOCKS + PREP_W1_BLOCKS + PREP_W2_BLOCKS)
__global__ __launch_bounds__(256) void prep_kernel(
    const float* __restrict__ x, const float* __restrict__ W1,
    const float* __restrict__ W2, const int* __restrict__ dst,
    ushort* __restrict__ xb, ushort* __restrict__ W1T,
    ushort* __restrict__ W2T, int* __restrict__ histT) {
    const int b = blockIdx.x;
    const int t = threadIdx.x;
    if (b < PREP_X_BLOCKS) {
        const size_t i = (size_t)b * 2048 + t * 8;
        float4 a = *reinterpret_cast<const float4*>(x + i);
        float4 c = *reinterpret_cast<const float4*>(x + i + 4);
        ushort v[8] = {f2b(a.x), f2b(a.y), f2b(a.z), f2b(a.w),
                       f2b(c.x), f2b(c.y), f2b(c.z), f2b(c.w)};
        *reinterpret_cast<short8*>(xb + i) = *reinterpret_cast<short8*>(v);
    } else if (b < PREP_X_BLOCKS + PREP_W1_BLOCKS) {
        const int i = (b - PREP_X_BLOCKS) * 256 + t;     // oc*128 + k
        const int oc = i >> 7, k = i & 127;
        W1T[i] = f2b(W1[k * HID_CH + oc]);
    } else if (b < PREP_TOTAL) {
        const int i = (b - PREP_X_BLOCKS - PREP_W1_BLOCKS) * 256 + t; // oc*256+k
        const int oc = i >> 8, k = i & 255;
        W2T[i] = f2b(W2[k * OUT_CH + oc]);
    } else {
        // ghist part
        __shared__ int h[NBK];
        const int bb = b - PREP_TOTAL;
        for (int k = t; k < NBK; k += 256) h[k] = 0;
        __syncthreads();
        const int base = bb * EPB;
        for (int i = t; i < EPB; i += 256)
            atomicAdd(&h[dst[base + i] >> 7], 1);
        __syncthreads();
        for (int k = t; k < NBK; k += 256) histT[k * BIN_BLOCKS + bb] = h[k];
    }
}

// ---------------------------------------------------------------------------
// Bucketing step 2a: per-bucket exclusive scan over the 256 block counts.
// ---------------------------------------------------------------------------
__global__ __launch_bounds__(256) void scanA_kernel(
    const int* __restrict__ histT, int* __restrict__ blockBaseP,
    int* __restrict__ bktTotal) {
    __shared__ int ts[256];
    const int bk = blockIdx.x, t = threadIdx.x;
    const int v = histT[bk * BIN_BLOCKS + t];
    ts[t] = v;
    __syncthreads();
    #pragma unroll
    for (int o = 1; o < 256; o <<= 1) {
        int add = (t >= o) ? ts[t - o] : 0;
        __syncthreads();
        ts[t] += add;
        __syncthreads();
    }
    blockBaseP[bk * BIN_BLOCKS + t] = ts[t] - v;
    if (t == 255) bktTotal[bk] = ts[255];
}

// ---------------------------------------------------------------------------
// Bucketing step 2b: exclusive scan of the 782 bucket totals (1 block).
// ---------------------------------------------------------------------------
__global__ __launch_bounds__(1024) void scanB_kernel(
    const int* __restrict__ bktTotal, int* __restrict__ bktBase) {
    __shared__ int ts[1024];
    const int t = threadIdx.x;
    const int v = (t < NBK) ? bktTotal[t] : 0;
    ts[t] = v;
    __syncthreads();
    #pragma unroll
    for (int o = 1; o < 1024; o <<= 1) {
        int add = (t >= o) ? ts[t - o] : 0;
        __syncthreads();
        ts[t] += add;
        __syncthreads();
    }
    if (t < NBK) bktBase[t] = ts[t] - v;
}

// ---------------------------------------------------------------------------
// Bucketing step 3: scatter packed entries (dl<<17 | src) into per-block
// contiguous runs inside each bucket region. LDS cursors only.
// ---------------------------------------------------------------------------
__global__ __launch_bounds__(256) void bin_kernel(
    const int* __restrict__ src, const int* __restrict__ dst,
    const int* __restrict__ blockBaseP, const int* __restrict__ bktBase,
    unsigned int* __restrict__ ebuf) {
    __shared__ int base[NBK];
    __shared__ int cur[NBK];
    const int b = blockIdx.x, t = threadIdx.x;
    for (int k = t; k < NBK; k += 256) {
        base[k] = bktBase[k] + blockBaseP[k * BIN_BLOCKS + b];
        cur[k] = 0;
    }
    __syncthreads();
    const int ebase = b * EPB;
    for (int i = t; i < EPB; i += 256) {
        const int d = dst[ebase + i];
        const int s = src[ebase + i];
        const int bk = d >> 7;
        const int r = atomicAdd(&cur[bk], 1);
        ebuf[base[bk] + r] = ((unsigned int)(d & 127) << 17) | (unsigned int)s;
    }
}

// ---------------------------------------------------------------------------
// Merged group+gather: block bk sorts its bucket's edges into an LDS list
// (hist -> scan -> scatter), then gathers straight from the list:
//   h_in[i] = bf16( (1+eps)*x[i] + sum_{j in N(i)} x[j] )   (fp32 accum)
// Gather: 8 groups of 32 lanes; per node, 8 independent row-load chains.
// ---------------------------------------------------------------------------
__global__ __launch_bounds__(256) void group_gather_kernel(
    const unsigned int* __restrict__ ebuf,
    const int* __restrict__ bktBase, const int* __restrict__ bktTotal,
    const ushort* __restrict__ xb, const float* __restrict__ eps_p,
    ushort* __restrict__ h_in) {
    __shared__ int list[GG_CAP];     // 16 KB: src indices sorted by local node
    __shared__ int hist[128];        // inclusive-scan counts
    __shared__ int st[128];          // node start offsets
    __shared__ int cur[128];
    const int bk = blockIdx.x, t = threadIdx.x;
    if (t < 128) hist[t] = 0;
    __syncthreads();
    const int start = bktBase[bk];
    const int cnt = min(bktTotal[bk], GG_CAP);
    for (int i = t; i < cnt; i += 256)
        atomicAdd(&hist[ebuf[start + i] >> 17], 1);
    __syncthreads();
    const int v = (t < 128) ? hist[t] : 0;
    #pragma unroll
    for (int o = 1; o < 128; o <<= 1) {
        int add = (t < 128 && t >= o) ? hist[t - o] : 0;
        __syncthreads();
        if (t < 128) hist[t] += add;
        __syncthreads();
    }
    if (t < 128) {
        const int excl = hist[t] - v;
        st[t] = excl;
        cur[t] = excl;
    }
    __syncthreads();
    for (int i = t; i < cnt; i += 256) {
        const unsigned int e = ebuf[start + i];
        const int dl = e >> 17;
        const int p = atomicAdd(&cur[dl], 1);
        list[p] = (int)(e & 0x1FFFF);
    }
    __syncthreads();

    // ---- gather phase ----
    const int grp = t >> 5;          // 8 groups of 32 lanes
    const int c = (t & 31) * 4;
    const float scale = 1.0f + eps_p[0];

    for (int dl = grp; dl < 128; dl += 8) {
        const int node = bk * 128 + dl;
        if (node >= N_NODES) continue;
        const int beg = st[dl];
        const int end = beg + (hist[dl] - ((dl == 0) ? 0 : 0)) - st[dl] + beg; // placeholder
        // (end computed below properly)
        const int e_end = hist[dl];  // inclusive scan == exclusive start of dl+1 == end of dl
        float4 A0 = {0,0,0,0}, A1 = {0,0,0,0}, A2 = {0,0,0,0}, A3 = {0,0,0,0};
        float4 A4 = {0,0,0,0}, A5 = {0,0,0,0}, A6 = {0,0,0,0}, A7 = {0,0,0,0};
        int e = beg;
        for (; e + 8 <= e_end; e += 8) {
            const int s0 = list[e + 0], s1 = list[e + 1];
            const int s2 = list[e + 2], s3 = list[e + 3];
            const int s4 = list[e + 4], s5 = list[e + 5];
            const int s6 = list[e + 6], s7 = list[e + 7];
            ushort4 v0 = *reinterpret_cast<const ushort4*>(xb + (size_t)s0 * IN_CH + c);
            ushort4 v1 = *reinterpret_cast<const ushort4*>(xb + (size_t)s1 * IN_CH + c);
            ushort4 v2 = *reinterpret_cast<const ushort4*>(xb + (size_t)s2 * IN_CH + c);
            ushort4 v3 = *reinterpret_cast<const ushort4*>(xb + (size_t)s3 * IN_CH + c);
            ushort4 v4 = *reinterpret_cast<const ushort4*>(xb + (size_t)s4 * IN_CH + c);
            ushort4 v5 = *reinterpret_cast<const ushort4*>(xb + (size_t)s5 * IN_CH + c);
            ushort4 v6 = *reinterpret_cast<const ushort4*>(xb + (size_t)s6 * IN_CH + c);
            ushort4 v7 = *reinterpret_cast<const ushort4*>(xb + (size_t)s7 * IN_CH + c);
            A0.x += b2f(v0.x); A0.y += b2f(v0.y); A0.z += b2f(v0.z); A0.w += b2f(v0.w);
            A1.x += b2f(v1.x); A1.y += b2f(v1.y); A1.z += b2f(v1.z); A1.w += b2f(v1.w);
            A2.x += b2f(v2.x); A2.y += b2f(v2.y); A2.z += b2f(v2.z); A2.w += b2f(v2.w);
            A3.x += b2f(v3.x); A3.y += b2f(v3.y); A3.z += b2f(v3.z); A3.w += b2f(v3.w);
            A4.x += b2f(v4.x); A4.y += b2f(v4.y); A4.z += b2f(v4.z); A4.w += b2f(v4.w);
            A5.x += b2f(v5.x); A5.y += b2f(v5.y); A5.z += b2f(v5.z); A5.w += b2f(v5.w);
            A6.x += b2f(v6.x); A6.y += b2f(v6.y); A6.z += b2f(v6.z); A6.w += b2f(v6.w);
            A7.x += b2f(v7.x); A7.y += b2f(v7.y); A7.z += b2f(v7.z); A7.w += b2f(v7.w);
        }
        for (; e < e_end; ++e) {
            const int s = list[e];
            ushort4 vv = *reinterpret_cast<const ushort4*>(xb + (size_t)s * IN_CH + c);
            A0.x += b2f(vv.x); A0.y += b2f(vv.y); A0.z += b2f(vv.z); A0.w += b2f(vv.w);
        }
        const float a0 = ((A0.x + A1.x) + (A2.x + A3.x)) + ((A4.x + A5.x) + (A6.x + A7.x));
        const float a1 = ((A0.y + A1.y) + (A2.y + A3.y)) + ((A4.y + A5.y) + (A6.y + A7.y));
        const float a2 = ((A0.z + A1.z) + (A2.z + A3.z)) + ((A4.z + A5.z) + (A6.z + A7.z));
        const float a3 = ((A0.w + A1.w) + (A2.w + A3.w)) + ((A4.w + A5.w) + (A6.w + A7.w));
        ushort4 sv = *reinterpret_cast<const ushort4*>(xb + (size_t)node * IN_CH + c);
        ushort4 o;
        o.x = f2b(scale * b2f(sv.x) + a0);
        o.y = f2b(scale * b2f(sv.y) + a1);
        o.z = f2b(scale * b2f(sv.z) + a2);
        o.w = f2b(scale * b2f(sv.w) + a3);
        *reinterpret_cast<ushort4*>(h_in + (size_t)node * IN_CH + c) = o;
    }
}

// ---------------------------------------------------------------------------
// Fused MLP (MFMA): out = log_softmax(relu(relu(h_in@W1+b1)@W2+b2))
// 512 thr = 8 waves x 16 rows = 128 rows/block. W1T staged into a 64 KB
// XOR-swizzled LDS buffer (re-staged with W2T after phase 1); h1 parked in
// per-wave padded LDS tiles.
// ---------------------------------------------------------------------------
#define H1_LD 264          // padded h1 row stride in halves
__global__ __launch_bounds__(512) void mlp_fused(
    const ushort* __restrict__ h_in,
    const ushort* __restrict__ W1T,
    const ushort* __restrict__ W2T,
    const float* __restrict__ b1,
    const float* __restrict__ b2,
    float* __restrict__ out) {
    __shared__ ushort wbuf[32768];            // 64 KB weights (W1T, then W2T)
    __shared__ ushort h1s[8][16 * H1_LD];     // 67.6 KB h1 tiles
    const int t    = threadIdx.x;
    const int w    = t >> 6;
    const int lane = t & 63;
    const int lr   = lane & 15;
    const int lk   = lane >> 4;
    const int row0 = blockIdx.x * 128 + w * 16;
    const int arow = row0 + lr;
    const int arc  = arow < N_NODES ? arow : N_NODES - 1;
    ushort* tile = h1s[w];
    const int sw = (lr & 7) << 3;             // read-side swizzle (halves)

    // ---- stage W1T (rows of 128 halves, swizzled); 64 halves/thread ----
    {
        const ushort* gw = W1T + t * 64;
        const int row = t >> 1;
        const int s = (row & 7) << 3;
        ushort* dstp = wbuf + row * 128;
        #pragma unroll
        for (int j = 0; j < 8; ++j) {
            short8 v = *reinterpret_cast<const short8*>(gw + j * 8);
            const int col = (t & 1) * 64 + j * 8;
            *reinterpret_cast<short8*>(dstp + (col ^ s)) = v;
        }
    }

    // A-frags for phase 1 (global h_in, L2-resident)
    short8 a[4];
    const ushort* ap = h_in + (size_t)arc * IN_CH + lk * 8;
    #pragma unroll
    for (int kk = 0; kk < 4; ++kk)
        a[kk] = *reinterpret_cast<const short8*>(ap + kk * 32);

    __syncthreads();

    // ---- phase 1: h1 = relu(h_in @ W1 + b1), 16 rows x 256 cols ----
    #pragma unroll
    for (int ct = 0; ct < 16; ++ct) {
        const ushort* bp = wbuf + (ct * 16 + lr) * 128;
        f32x4 acc = (f32x4){0.f, 0.f, 0.f, 0.f};
        #pragma unroll
        for (int kk = 0; kk < 4; ++kk) {
            short8 b = *reinterpret_cast<const short8*>(bp + ((lk * 8 + kk * 32) ^ sw));
            acc = __builtin_amdgcn_mfma_f32_16x16x32_bf16(a[kk], b, acc, 0, 0, 0);
        }
        const float bb = b1[ct * 16 + lr];
        #pragma unroll
        for (int r = 0; r < 4; ++r) {
            float v = fmaxf(acc[r] + bb, 0.0f);
            tile[(lk * 4 + r) * H1_LD + ct * 16 + lr] = f2b(v);
        }
    }

    __syncthreads();   // all waves done reading W1 from wbuf

    // ---- stage W2T (rows of 256 halves, swizzled) ----
    {
        const ushort* gw = W2T + t * 64;
        const int row = t >> 2;
        const int s = (row & 7) << 3;
        ushort* dstp = wbuf + row * 256;
        #pragma unroll
        for (int j = 0; j < 8; ++j) {
            short8 v = *reinterpret_cast<const short8*>(gw + j * 8);
            const int col = (t & 3) * 64 + j * 8;
            *reinterpret_cast<short8*>(dstp + (col ^ s)) = v;
        }
    }

    // A2-frags from own (wave-private) tile — safe before the barrier
    short8 a2[8];
    #pragma unroll
    for (int kk = 0; kk < 8; ++kk)
        a2[kk] = *reinterpret_cast<const short8*>(tile + lr * H1_LD + lk * 8 + kk * 32);

    __syncthreads();   // W2 staged

    // ---- phase 2: out = lsm(relu(h1 @ W2 + b2)), 16 rows x 128 cols ----
    f32x4 acc2[8];
    #pragma unroll
    for (int ct = 0; ct < 8; ++ct) acc2[ct] = (f32x4){0.f, 0.f, 0.f, 0.f};

    #pragma unroll
    for (int ct = 0; ct < 8; ++ct) {
        const ushort* bp = wbuf + (ct * 16 + lr) * 256;
        #pragma unroll
        for (int kk = 0; kk < 8; ++kk) {
            short8 b = *reinterpret_cast<const short8*>(bp + ((lk * 8 + kk * 32) ^ sw));
            acc2[ct] = __builtin_amdgcn_mfma_f32_16x16x32_bf16(a2[kk], b, acc2[ct], 0, 0, 0);
        }
    }

    float bias[8];
    #pragma unroll
    for (int ct = 0; ct < 8; ++ct) bias[ct] = b2[ct * 16 + lr];

    const int orow0 = row0 + lk * 4;
    #pragma unroll
    for (int r = 0; r < 4; ++r) {
        float v[8];
        float m = -1e30f;
        #pragma unroll
        for (int ct = 0; ct < 8; ++ct) {
            v[ct] = fmaxf(acc2[ct][r] + bias[ct], 0.0f);
            m = fmaxf(m, v[ct]);
        }
        #pragma unroll
        for (int o = 1; o < 16; o <<= 1) m = fmaxf(m, __shfl_xor(m, o));
        float s = 0.0f;
        #pragma unroll
        for (int ct = 0; ct < 8; ++ct) s += __expf(v[ct] - m);
        #pragma unroll
        for (int o = 1; o < 16; o <<= 1) s += __shfl_xor(s, o);
        const float lse = m + __logf(s);
        const int orow = orow0 + r;
        if (orow < N_NODES) {
            #pragma unroll
            for (int ct = 0; ct < 8; ++ct)
                out[(size_t)orow * OUT_CH + ct * 16 + lr] = v[ct] - lse;
        }
    }
}

extern "C" void kernel_launch(void* const* d_in, const int* in_sizes, int n_in,
                              void* d_out, int out_size, void* d_ws, size_t ws_size,
                              hipStream_t stream) {
    const float* x    = (const float*)d_in[0];
    const int*   ei   = (const int*)d_in[1];
    const float* W1   = (const float*)d_in[2];
    const float* b1   = (const float*)d_in[3];
    const float* W2   = (const float*)d_in[4];
    const float* b2   = (const float*)d_in[5];
    const float* eps  = (const float*)d_in[6];
    float* out = (float*)d_out;

    // workspace layout
    ushort* xb   = (ushort*)d_ws;                          // 12.8M ushort
    ushort* h_in = xb + (size_t)N_NODES * IN_CH;           // 12.8M
    ushort* W1T  = h_in + (size_t)N_NODES * IN_CH;         // 32768
    ushort* W2T  = W1T + IN_CH * HID_CH;                   // 32768
    int* histT      = (int*)(W2T + HID_CH * OUT_CH);       // NBK*256
    int* blockBaseP = histT + NBK * BIN_BLOCKS;            // NBK*256
    int* bktTotal   = blockBaseP + NBK * BIN_BLOCKS;       // NBK
    int* bktBase    = bktTotal + NBK;                      // NBK
    unsigned int* ebuf = (unsigned int*)(bktBase + NBK);   // 1.6M

    const int* src = ei;
    const int* dst = ei + N_EDGES;

    prep_kernel<<<PREP_TOTAL + BIN_BLOCKS, 256, 0, stream>>>(
        x, W1, W2, dst, xb, W1T, W2T, histT);
    scanA_kernel<<<NBK, 256, 0, stream>>>(histT, blockBaseP, bktTotal);
    scanB_kernel<<<1, 1024, 0, stream>>>(bktTotal, bktBase);
    bin_kernel<<<BIN_BLOCKS, 256, 0, stream>>>(src, dst, blockBaseP, bktBase, ebuf);
    group_gather_kernel<<<NBK, 256, 0, stream>>>(ebuf, bktBase, bktTotal, xb, eps, h_in);
    mlp_fused<<<(N_NODES + 127) / 128, 512, 0, stream>>>(h_in, W1T, W2T, b1, b2, out);
}

// Round 10
// 167.744 us; speedup vs baseline: 1.2888x; 1.2888x over previous
//
#include <hip/hip_runtime.h>

#define N_NODES 100000
#define IN_CH 128
#define HID_CH 256
#define OUT_CH 128
#define N_EDGES 1600000

#define NBK 782                                   // ceil(N_NODES/128) buckets of 128 nodes
#define BIN_BLOCKS 256
#define EPB (N_EDGES / BIN_BLOCKS)                // 6250 edges per bin block

typedef __attribute__((ext_vector_type(8))) short short8;
typedef __attribute__((ext_vector_type(4))) float f32x4;

// bf16 <-> f32 helpers (bit ops; finite data only)
__device__ __forceinline__ float b2f(ushort u) {
    unsigned int x = ((unsigned int)u) << 16;
    return __uint_as_float(x);
}
__device__ __forceinline__ ushort f2b(float f) {
    unsigned int u = __float_as_uint(f);
    u += 0x7FFFu + ((u >> 16) & 1u);   // round-to-nearest-even
    return (ushort)(u >> 16);
}

// ---------------------------------------------------------------------------
// Prep (+ fused ghist): x fp32 -> xb bf16 ; W1 -> W1T ; W2 -> W2T ;
// last 256 blocks: per-(block,bucket) dst histogram (transposed store).
// ---------------------------------------------------------------------------
#define PREP_X_BLOCKS 6250
#define PREP_W1_BLOCKS 128
#define PREP_W2_BLOCKS 128
#define PREP_TOTAL (PREP_X_BLOCKS + PREP_W1_BLOCKS + PREP_W2_BLOCKS)
__global__ __launch_bounds__(256) void prep_kernel(
    const float* __restrict__ x, const float* __restrict__ W1,
    const float* __restrict__ W2, const int* __restrict__ dst,
    ushort* __restrict__ xb, ushort* __restrict__ W1T,
    ushort* __restrict__ W2T, int* __restrict__ histT) {
    const int b = blockIdx.x;
    const int t = threadIdx.x;
    if (b < PREP_X_BLOCKS) {
        const size_t i = (size_t)b * 2048 + t * 8;
        float4 a = *reinterpret_cast<const float4*>(x + i);
        float4 c = *reinterpret_cast<const float4*>(x + i + 4);
        ushort v[8] = {f2b(a.x), f2b(a.y), f2b(a.z), f2b(a.w),
                       f2b(c.x), f2b(c.y), f2b(c.z), f2b(c.w)};
        *reinterpret_cast<short8*>(xb + i) = *reinterpret_cast<short8*>(v);
    } else if (b < PREP_X_BLOCKS + PREP_W1_BLOCKS) {
        const int i = (b - PREP_X_BLOCKS) * 256 + t;     // oc*128 + k
        const int oc = i >> 7, k = i & 127;
        W1T[i] = f2b(W1[k * HID_CH + oc]);
    } else if (b < PREP_TOTAL) {
        const int i = (b - PREP_X_BLOCKS - PREP_W1_BLOCKS) * 256 + t; // oc*256+k
        const int oc = i >> 8, k = i & 255;
        W2T[i] = f2b(W2[k * OUT_CH + oc]);
    } else {
        __shared__ int h[NBK];
        const int bb = b - PREP_TOTAL;
        for (int k = t; k < NBK; k += 256) h[k] = 0;
        __syncthreads();
        const int base = bb * EPB;
        for (int i = t; i < EPB; i += 256)
            atomicAdd(&h[dst[base + i] >> 7], 1);
        __syncthreads();
        for (int k = t; k < NBK; k += 256) histT[k * BIN_BLOCKS + bb] = h[k];
    }
}

// ---------------------------------------------------------------------------
// Bucketing step 2a: per-bucket exclusive scan over the 256 block counts.
// ---------------------------------------------------------------------------
__global__ __launch_bounds__(256) void scanA_kernel(
    const int* __restrict__ histT, int* __restrict__ blockBaseP,
    int* __restrict__ bktTotal) {
    __shared__ int ts[256];
    const int bk = blockIdx.x, t = threadIdx.x;
    const int v = histT[bk * BIN_BLOCKS + t];
    ts[t] = v;
    __syncthreads();
    #pragma unroll
    for (int o = 1; o < 256; o <<= 1) {
        int add = (t >= o) ? ts[t - o] : 0;
        __syncthreads();
        ts[t] += add;
        __syncthreads();
    }
    blockBaseP[bk * BIN_BLOCKS + t] = ts[t] - v;
    if (t == 255) bktTotal[bk] = ts[255];
}

// ---------------------------------------------------------------------------
// Bucketing step 2b: exclusive scan of the 782 bucket totals (1 block).
// ---------------------------------------------------------------------------
__global__ __launch_bounds__(1024) void scanB_kernel(
    const int* __restrict__ bktTotal, int* __restrict__ bktBase) {
    __shared__ int ts[1024];
    const int t = threadIdx.x;
    const int v = (t < NBK) ? bktTotal[t] : 0;
    ts[t] = v;
    __syncthreads();
    #pragma unroll
    for (int o = 1; o < 1024; o <<= 1) {
        int add = (t >= o) ? ts[t - o] : 0;
        __syncthreads();
        ts[t] += add;
        __syncthreads();
    }
    if (t < NBK) bktBase[t] = ts[t] - v;
}

// ---------------------------------------------------------------------------
// Bucketing step 3: scatter packed entries (dl<<17 | src) into per-block
// contiguous runs inside each bucket region. LDS cursors only.
// ---------------------------------------------------------------------------
__global__ __launch_bounds__(256) void bin_kernel(
    const int* __restrict__ src, const int* __restrict__ dst,
    const int* __restrict__ blockBaseP, const int* __restrict__ bktBase,
    unsigned int* __restrict__ ebuf) {
    __shared__ int base[NBK];
    __shared__ int cur[NBK];
    const int b = blockIdx.x, t = threadIdx.x;
    for (int k = t; k < NBK; k += 256) {
        base[k] = bktBase[k] + blockBaseP[k * BIN_BLOCKS + b];
        cur[k] = 0;
    }
    __syncthreads();
    const int ebase = b * EPB;
    for (int i = t; i < EPB; i += 256) {
        const int d = dst[ebase + i];
        const int s = src[ebase + i];
        const int bk = d >> 7;
        const int r = atomicAdd(&cur[bk], 1);
        ebuf[base[bk] + r] = ((unsigned int)(d & 127) << 17) | (unsigned int)s;
    }
}

// ---------------------------------------------------------------------------
// Bucketing step 4: node-sort each bucket -> exact CSR (global csr_src/offs).
// ---------------------------------------------------------------------------
__global__ __launch_bounds__(256) void group_kernel(
    const unsigned int* __restrict__ ebuf,
    const int* __restrict__ bktBase, const int* __restrict__ bktTotal,
    int* __restrict__ csr_src, int* __restrict__ offs) {
    __shared__ int hist[128];
    __shared__ int cur[128];
    const int bk = blockIdx.x, t = threadIdx.x;
    if (t < 128) hist[t] = 0;
    __syncthreads();
    const int start = bktBase[bk];
    const int cnt   = bktTotal[bk];
    for (int i = t; i < cnt; i += 256)
        atomicAdd(&hist[ebuf[start + i] >> 17], 1);
    __syncthreads();
    int v = (t < 128) ? hist[t] : 0;
    #pragma unroll
    for (int o = 1; o < 128; o <<= 1) {
        int add = (t < 128 && t >= o) ? hist[t - o] : 0;
        __syncthreads();
        if (t < 128) hist[t] += add;
        __syncthreads();
    }
    if (t < 128) {
        const int excl = hist[t] - v;
        cur[t] = excl;
        const int node = bk * 128 + t;
        if (node < N_NODES) offs[node] = start + excl;
    }
    if (bk == 0 && t == 0) offs[N_NODES] = N_EDGES;
    __syncthreads();
    for (int i = t; i < cnt; i += 256) {
        const unsigned int e = ebuf[start + i];
        const int dl = e >> 17;
        const int p = atomicAdd(&cur[dl], 1);
        csr_src[start + p] = (int)(e & 0x1FFFF);
    }
}

// ---------------------------------------------------------------------------
// Gather-aggregate fused with GIN self-term (bf16 rows, fp32 accum):
//   h_in[i] = bf16( (1+eps)*x[i] + sum_{j in N(i)} x[j] )
// 16 nodes/block, 16 lanes/node, short8 (16 B) per lane -> 16 load instrs
// per 256 B row (half of the 8 B version). 4 independent acc chains per node
// via __shfl broadcast of a 16-edge index tile.
// ---------------------------------------------------------------------------
__global__ __launch_bounds__(256) void gather_kernel(
    const ushort* __restrict__ xb,
    const float* __restrict__ eps_p,
    const int* __restrict__ offs,
    const int* __restrict__ csr_src,
    ushort* __restrict__ h_in) {
    const int node = blockIdx.x * 16 + (threadIdx.x >> 4);
    const int l16 = threadIdx.x & 15;
    const int c = l16 * 8;                 // 8 channels per lane
    const int beg = offs[node];
    const int end = offs[node + 1];

    float a0[8], a1[8], a2[8], a3[8];
    #pragma unroll
    for (int j = 0; j < 8; ++j) { a0[j] = 0.f; a1[j] = 0.f; a2[j] = 0.f; a3[j] = 0.f; }

    for (int base = beg; base < end; base += 16) {
        const int nn = min(16, end - base);
        const int sidx = csr_src[base + min(l16, nn - 1)];
        int i = 0;
        for (; i + 4 <= nn; i += 4) {
            const int s0 = __shfl(sidx, i + 0, 16);
            const int s1 = __shfl(sidx, i + 1, 16);
            const int s2 = __shfl(sidx, i + 2, 16);
            const int s3 = __shfl(sidx, i + 3, 16);
            short8 v0 = *reinterpret_cast<const short8*>(xb + (size_t)s0 * IN_CH + c);
            short8 v1 = *reinterpret_cast<const short8*>(xb + (size_t)s1 * IN_CH + c);
            short8 v2 = *reinterpret_cast<const short8*>(xb + (size_t)s2 * IN_CH + c);
            short8 v3 = *reinterpret_cast<const short8*>(xb + (size_t)s3 * IN_CH + c);
            #pragma unroll
            for (int j = 0; j < 8; ++j) {
                a0[j] += b2f((ushort)v0[j]);
                a1[j] += b2f((ushort)v1[j]);
                a2[j] += b2f((ushort)v2[j]);
                a3[j] += b2f((ushort)v3[j]);
            }
        }
        for (; i < nn; ++i) {
            const int s = __shfl(sidx, i, 16);
            short8 v = *reinterpret_cast<const short8*>(xb + (size_t)s * IN_CH + c);
            #pragma unroll
            for (int j = 0; j < 8; ++j) a0[j] += b2f((ushort)v[j]);
        }
    }

    const float scale = 1.0f + eps_p[0];
    short8 sv = *reinterpret_cast<const short8*>(xb + (size_t)node * IN_CH + c);
    ushort o[8];
    #pragma unroll
    for (int j = 0; j < 8; ++j) {
        const float aggr = (a0[j] + a1[j]) + (a2[j] + a3[j]);
        o[j] = f2b(scale * b2f((ushort)sv[j]) + aggr);
    }
    *reinterpret_cast<short8*>(h_in + (size_t)node * IN_CH + c) =
        *reinterpret_cast<short8*>(o);
}

// ---------------------------------------------------------------------------
// Fused MLP (MFMA): out = log_softmax(relu(relu(h_in@W1+b1)@W2+b2))
// 512 thr = 8 waves x 16 rows = 128 rows/block. W1T staged into a 64 KB
// XOR-swizzled LDS buffer (re-staged with W2T after phase 1); h1 parked in
// per-wave padded LDS tiles.
// ---------------------------------------------------------------------------
#define H1_LD 264          // padded h1 row stride in halves
__global__ __launch_bounds__(512) void mlp_fused(
    const ushort* __restrict__ h_in,
    const ushort* __restrict__ W1T,
    const ushort* __restrict__ W2T,
    const float* __restrict__ b1,
    const float* __restrict__ b2,
    float* __restrict__ out) {
    __shared__ ushort wbuf[32768];            // 64 KB weights (W1T, then W2T)
    __shared__ ushort h1s[8][16 * H1_LD];     // 67.6 KB h1 tiles
    const int t    = threadIdx.x;
    const int w    = t >> 6;
    const int lane = t & 63;
    const int lr   = lane & 15;
    const int lk   = lane >> 4;
    const int row0 = blockIdx.x * 128 + w * 16;
    const int arow = row0 + lr;
    const int arc  = arow < N_NODES ? arow : N_NODES - 1;
    ushort* tile = h1s[w];
    const int sw = (lr & 7) << 3;             // read-side swizzle (halves)

    // ---- stage W1T (rows of 128 halves, swizzled); 64 halves/thread ----
    {
        const ushort* gw = W1T + t * 64;
        const int row = t >> 1;
        const int s = (row & 7) << 3;
        ushort* dstp = wbuf + row * 128;
        #pragma unroll
        for (int j = 0; j < 8; ++j) {
            short8 v = *reinterpret_cast<const short8*>(gw + j * 8);
            const int col = (t & 1) * 64 + j * 8;
            *reinterpret_cast<short8*>(dstp + (col ^ s)) = v;
        }
    }

    // A-frags for phase 1 (global h_in, L2-resident)
    short8 a[4];
    const ushort* ap = h_in + (size_t)arc * IN_CH + lk * 8;
    #pragma unroll
    for (int kk = 0; kk < 4; ++kk)
        a[kk] = *reinterpret_cast<const short8*>(ap + kk * 32);

    __syncthreads();

    // ---- phase 1: h1 = relu(h_in @ W1 + b1), 16 rows x 256 cols ----
    #pragma unroll
    for (int ct = 0; ct < 16; ++ct) {
        const ushort* bp = wbuf + (ct * 16 + lr) * 128;
        f32x4 acc = (f32x4){0.f, 0.f, 0.f, 0.f};
        #pragma unroll
        for (int kk = 0; kk < 4; ++kk) {
            short8 b = *reinterpret_cast<const short8*>(bp + ((lk * 8 + kk * 32) ^ sw));
            acc = __builtin_amdgcn_mfma_f32_16x16x32_bf16(a[kk], b, acc, 0, 0, 0);
        }
        const float bb = b1[ct * 16 + lr];
        #pragma unroll
        for (int r = 0; r < 4; ++r) {
            float v = fmaxf(acc[r] + bb, 0.0f);
            tile[(lk * 4 + r) * H1_LD + ct * 16 + lr] = f2b(v);
        }
    }

    __syncthreads();   // all waves done reading W1 from wbuf

    // ---- stage W2T (rows of 256 halves, swizzled) ----
    {
        const ushort* gw = W2T + t * 64;
        const int row = t >> 2;
        const int s = (row & 7) << 3;
        ushort* dstp = wbuf + row * 256;
        #pragma unroll
        for (int j = 0; j < 8; ++j) {
            short8 v = *reinterpret_cast<const short8*>(gw + j * 8);
            const int col = (t & 3) * 64 + j * 8;
            *reinterpret_cast<short8*>(dstp + (col ^ s)) = v;
        }
    }

    // A2-frags from own (wave-private) tile — safe before the barrier
    short8 a2[8];
    #pragma unroll
    for (int kk = 0; kk < 8; ++kk)
        a2[kk] = *reinterpret_cast<const short8*>(tile + lr * H1_LD + lk * 8 + kk * 32);

    __syncthreads();   // W2 staged

    // ---- phase 2: out = lsm(relu(h1 @ W2 + b2)), 16 rows x 128 cols ----
    f32x4 acc2[8];
    #pragma unroll
    for (int ct = 0; ct < 8; ++ct) acc2[ct] = (f32x4){0.f, 0.f, 0.f, 0.f};

    #pragma unroll
    for (int ct = 0; ct < 8; ++ct) {
        const ushort* bp = wbuf + (ct * 16 + lr) * 256;
        #pragma unroll
        for (int kk = 0; kk < 8; ++kk) {
            short8 b = *reinterpret_cast<const short8*>(bp + ((lk * 8 + kk * 32) ^ sw));
            acc2[ct] = __builtin_amdgcn_mfma_f32_16x16x32_bf16(a2[kk], b, acc2[ct], 0, 0, 0);
        }
    }

    float bias[8];
    #pragma unroll
    for (int ct = 0; ct < 8; ++ct) bias[ct] = b2[ct * 16 + lr];

    const int orow0 = row0 + lk * 4;
    #pragma unroll
    for (int r = 0; r < 4; ++r) {
        float v[8];
        float m = -1e30f;
        #pragma unroll
        for (int ct = 0; ct < 8; ++ct) {
            v[ct] = fmaxf(acc2[ct][r] + bias[ct], 0.0f);
            m = fmaxf(m, v[ct]);
        }
        #pragma unroll
        for (int o = 1; o < 16; o <<= 1) m = fmaxf(m, __shfl_xor(m, o));
        float s = 0.0f;
        #pragma unroll
        for (int ct = 0; ct < 8; ++ct) s += __expf(v[ct] - m);
        #pragma unroll
        for (int o = 1; o < 16; o <<= 1) s += __shfl_xor(s, o);
        const float lse = m + __logf(s);
        const int orow = orow0 + r;
        if (orow < N_NODES) {
            #pragma unroll
            for (int ct = 0; ct < 8; ++ct)
                out[(size_t)orow * OUT_CH + ct * 16 + lr] = v[ct] - lse;
        }
    }
}

extern "C" void kernel_launch(void* const* d_in, const int* in_sizes, int n_in,
                              void* d_out, int out_size, void* d_ws, size_t ws_size,
                              hipStream_t stream) {
    const float* x    = (const float*)d_in[0];
    const int*   ei   = (const int*)d_in[1];
    const float* W1   = (const float*)d_in[2];
    const float* b1   = (const float*)d_in[3];
    const float* W2   = (const float*)d_in[4];
    const float* b2   = (const float*)d_in[5];
    const float* eps  = (const float*)d_in[6];
    float* out = (float*)d_out;

    // workspace layout
    ushort* xb   = (ushort*)d_ws;                          // 12.8M ushort
    ushort* h_in = xb + (size_t)N_NODES * IN_CH;           // 12.8M
    ushort* W1T  = h_in + (size_t)N_NODES * IN_CH;         // 32768
    ushort* W2T  = W1T + IN_CH * HID_CH;                   // 32768
    int* histT      = (int*)(W2T + HID_CH * OUT_CH);       // NBK*256
    int* blockBaseP = histT + NBK * BIN_BLOCKS;            // NBK*256
    int* bktTotal   = blockBaseP + NBK * BIN_BLOCKS;       // NBK
    int* bktBase    = bktTotal + NBK;                      // NBK
    int* offs       = bktBase + NBK;                       // N_NODES+1
    unsigned int* ebuf = (unsigned int*)(offs + N_NODES + 2); // 1.6M
    int* csr_src    = (int*)(ebuf + N_EDGES);              // 1.6M

    const int* src = ei;
    const int* dst = ei + N_EDGES;

    prep_kernel<<<PREP_TOTAL + BIN_BLOCKS, 256, 0, stream>>>(
        x, W1, W2, dst, xb, W1T, W2T, histT);
    scanA_kernel<<<NBK, 256, 0, stream>>>(histT, blockBaseP, bktTotal);
    scanB_kernel<<<1, 1024, 0, stream>>>(bktTotal, bktBase);
    bin_kernel<<<BIN_BLOCKS, 256, 0, stream>>>(src, dst, blockBaseP, bktBase, ebuf);
    group_kernel<<<NBK, 256, 0, stream>>>(ebuf, bktBase, bktTotal, csr_src, offs);
    gather_kernel<<<N_NODES / 16, 256, 0, stream>>>(xb, eps, offs, csr_src, h_in);
    mlp_fused<<<(N_NODES + 127) / 128, 512, 0, stream>>>(h_in, W1T, W2T, b1, b2, out);
}